// Round 5
// baseline (180.660 us; speedup 1.0000x reference)
//
#include <hip/hip_runtime.h>

// Hierarchical sparse attention (binary tree), MI355X gfx950.
// B=4, S=4096, H=8, D=64, f32.
// Wave layout: 4 items x 16 lanes, lane holds 4 dims (float4).

#define S 4096
#define H 8
#define D 64
#define B 4
#define NINT 4094   // internal nodes per (b,h): levels 1..11 (root unused)
#define NBH 32      // B*H
#define SCALE 0.125f

__device__ inline float red16(float x) {
    x += __shfl_xor(x, 1);
    x += __shfl_xor(x, 2);
    x += __shfl_xor(x, 4);
    x += __shfl_xor(x, 8);
    return x;
}

__device__ inline float dot4(const float4 a, const float4 b) {
    return a.x * b.x + a.y * b.y + a.z * b.z + a.w * b.w;
}

// parent(k,v) from two children: softmax-weighted merge (16-lane reduce).
__device__ inline void combine(const float4 k0, const float4 k1,
                               const float4 v0, const float4 v1,
                               float4& kp, float4& vp) {
    kp.x = 0.5f * (k0.x + k1.x);
    kp.y = 0.5f * (k0.y + k1.y);
    kp.z = 0.5f * (k0.z + k1.z);
    kp.w = 0.5f * (k0.w + k1.w);
    float pss = red16(dot4(kp, kp)) * SCALE;
    float p0  = red16(dot4(kp, k0)) * SCALE;
    float p1  = red16(dot4(kp, k1)) * SCALE;
    float m  = fmaxf(pss, fmaxf(p0, p1));
    float es = __expf(pss - m), e0 = __expf(p0 - m), e1 = __expf(p1 - m);
    float inv = 1.0f / (es + e0 + e1 + 1e-9f);
    float h = 0.5f * es;
    vp.x = ((h + e0) * v0.x + (h + e1) * v1.x) * inv;
    vp.y = ((h + e0) * v0.y + (h + e1) * v1.y) * inv;
    vp.z = ((h + e0) * v0.z + (h + e1) * v1.z) * inv;
    vp.w = ((h + e0) * v0.w + (h + e1) * v1.w) * inv;
}

// Levels 1..6: one block per (bh, 64-leaf chunk); ping-pong LDS (24 KB).
__global__ __launch_bounds__(256) void tree_chunk(
    const float* __restrict__ k, const float* __restrict__ v,
    float* __restrict__ kt, float* __restrict__ vt)
{
    __shared__ float lkA[32 * 64], lvA[32 * 64];
    __shared__ float lkB[16 * 64], lvB[16 * 64];
    const int t = threadIdx.x;
    const int sub = t & 15;
    const int pg = t >> 4;           // 0..15
    const int blk = blockIdx.x;
    const int c = blk & 63;          // 64-leaf chunk
    const int bh = blk >> 6;
    const int b = bh >> 3, h = bh & 7;

    // level 1: 32 parents, children = global leaves
#pragma unroll
    for (int r = 0; r < 2; ++r) {
        int j = pg + r * 16;
        int s0 = c * 64 + 2 * j;
        size_t a0 = ((((size_t)b * S + s0) * H + h) * D) + sub * 4;
        float4 k0 = *(const float4*)(k + a0);
        float4 k1 = *(const float4*)(k + a0 + H * D);
        float4 v0 = *(const float4*)(v + a0);
        float4 v1 = *(const float4*)(v + a0 + H * D);
        float4 kp, vp;
        combine(k0, k1, v0, v1, kp, vp);
        *(float4*)(lkA + j * 64 + sub * 4) = kp;
        *(float4*)(lvA + j * 64 + sub * 4) = vp;
        size_t g = ((size_t)bh * NINT + c * 32 + j) * 64 + sub * 4;
        *(float4*)(kt + g) = kp;
        *(float4*)(vt + g) = vp;
    }
    __syncthreads();

    float *sk = lkA, *sv = lvA, *dk = lkB, *dv = lvB;
#pragma unroll
    for (int l = 2; l <= 6; ++l) {
        int np = 64 >> l;            // 16,8,4,2,1
        int goff = S - (S >> (l - 1));
        if (pg < np) {
            int j = pg;
            float4 k0 = *(const float4*)(sk + (2 * j) * 64 + sub * 4);
            float4 k1 = *(const float4*)(sk + (2 * j + 1) * 64 + sub * 4);
            float4 v0 = *(const float4*)(sv + (2 * j) * 64 + sub * 4);
            float4 v1 = *(const float4*)(sv + (2 * j + 1) * 64 + sub * 4);
            float4 kp, vp;
            combine(k0, k1, v0, v1, kp, vp);
            if (l < 6) {
                *(float4*)(dk + j * 64 + sub * 4) = kp;
                *(float4*)(dv + j * 64 + sub * 4) = vp;
            }
            size_t g = ((size_t)bh * NINT + goff + c * np + j) * 64 + sub * 4;
            *(float4*)(kt + g) = kp;
            *(float4*)(vt + g) = vp;
        }
        __syncthreads();
        float* tp;
        tp = sk; sk = dk; dk = tp;
        tp = sv; sv = dv; dv = tp;
    }
}

// Levels 7..11: one block per bh, from the 64 level-6 nodes.
__global__ __launch_bounds__(256) void tree_top(
    float* __restrict__ kt, float* __restrict__ vt)
{
    __shared__ float lkA[64 * 64], lvA[64 * 64];
    __shared__ float lkB[32 * 64], lvB[32 * 64];
    const int t = threadIdx.x;
    const int sub = t & 15;
    const int pg = t >> 4;
    const int bh = blockIdx.x;

    // load level 6 (64 nodes, off=3968) into A
    for (int i = t; i < 1024; i += 256) {
        size_t g = ((size_t)bh * NINT + 3968) * 64 + i * 4;
        *(float4*)(lkA + i * 4) = *(const float4*)(kt + g);
        *(float4*)(lvA + i * 4) = *(const float4*)(vt + g);
    }
    __syncthreads();

    float *sk = lkA, *sv = lvA, *dk = lkB, *dv = lvB;
    int cn = 64;
#pragma unroll
    for (int l = 7; l <= 11; ++l) {
        int np = cn >> 1;            // 32,16,8,4,2
        int goff = S - (S >> (l - 1));
        for (int j = pg; j < np; j += 16) {
            float4 k0 = *(const float4*)(sk + (2 * j) * 64 + sub * 4);
            float4 k1 = *(const float4*)(sk + (2 * j + 1) * 64 + sub * 4);
            float4 v0 = *(const float4*)(sv + (2 * j) * 64 + sub * 4);
            float4 v1 = *(const float4*)(sv + (2 * j + 1) * 64 + sub * 4);
            float4 kp, vp;
            combine(k0, k1, v0, v1, kp, vp);
            if (l < 11) {
                *(float4*)(dk + j * 64 + sub * 4) = kp;
                *(float4*)(dv + j * 64 + sub * 4) = vp;
            }
            size_t g = ((size_t)bh * NINT + goff + j) * 64 + sub * 4;
            *(float4*)(kt + g) = kp;
            *(float4*)(vt + g) = vp;
        }
        __syncthreads();
        float* tp;
        tp = sk; sk = dk; dk = tp;
        tp = sv; sv = dv; dv = tp;
        cn = np;
    }
}

// Wave = 4 heads of one query s, lane = 4 dims.
// Straight-line: all 12 level loads issued unconditionally for ILP, but
// INACTIVE levels load a hot dummy address (tree node 0 / own leaf) so HBM
// traffic stays at the conditional version's level. Scores masked afterwards.
__global__ __launch_bounds__(256, 3) void attn(
    const float* __restrict__ q, const float* __restrict__ k,
    const float* __restrict__ v,
    const float* __restrict__ kt, const float* __restrict__ vt,
    float* __restrict__ out)
{
    int t = blockIdx.x * 256 + threadIdx.x;
    int lane = t & 63;
    int sub = lane & 15;
    int qi = lane >> 4;
    int w = t >> 6;
    int hg = w & 1;
    int s = (w >> 1) & (S - 1);
    int b = w >> 13;
    int h = hg * 4 + qi;
    int bh = b * 8 + h;
    size_t qa = ((((size_t)b * S + s) * H + h) * D) + sub * 4;

    float4 q4 = *(const float4*)(q + qa);
    float4 k4 = *(const float4*)(k + qa);
    float4 v4 = *(const float4*)(v + qa);

    // level 0: sibling leaf s-1 when s odd, else self (hot line, discarded)
    int sl0 = s ^ (s & 1);
    size_t sa = ((((size_t)b * S + sl0) * H + h) * D) + sub * 4;
    float4 kc0 = *(const float4*)(k + sa);
    float4 vc0 = *(const float4*)(v + sa);

    // levels 1..11: sibling node when active, else tree node 0 (hot, discarded)
    size_t tb = (size_t)bh * NINT;
    float4 kc[11], vc[11];
#pragma unroll
    for (int l = 1; l <= 11; ++l) {
        int bit = (s >> l) & 1;
        int node = bit ? ((S - (S >> (l - 1))) + ((s >> l) ^ 1)) : 0;
        size_t a = (tb + node) * 64 + sub * 4;
        kc[l - 1] = *(const float4*)(kt + a);
        vc[l - 1] = *(const float4*)(vt + a);
    }

    float ss = red16(dot4(q4, k4)) * SCALE;
    float sc[12];
    sc[0] = red16(dot4(q4, kc0)) * SCALE;
#pragma unroll
    for (int l = 1; l <= 11; ++l)
        sc[l] = red16(dot4(q4, kc[l - 1])) * SCALE;

#pragma unroll
    for (int l = 0; l < 12; ++l)
        sc[l] = ((s >> l) & 1) ? sc[l] : -1e38f;   // branchless mask

    float m = ss;
#pragma unroll
    for (int l = 0; l < 12; ++l) m = fmaxf(m, sc[l]);

    float es = __expf(ss - m);
    float denom = es;
    float4 acc;
    acc.x = es * v4.x; acc.y = es * v4.y; acc.z = es * v4.z; acc.w = es * v4.w;

    float e0 = __expf(sc[0] - m);    // 0 when masked
    denom += e0;
    acc.x += e0 * vc0.x; acc.y += e0 * vc0.y;
    acc.z += e0 * vc0.z; acc.w += e0 * vc0.w;
#pragma unroll
    for (int l = 1; l <= 11; ++l) {
        float e = __expf(sc[l] - m);
        denom += e;
        acc.x += e * vc[l - 1].x;
        acc.y += e * vc[l - 1].y;
        acc.z += e * vc[l - 1].z;
        acc.w += e * vc[l - 1].w;
    }
    float inv = 1.0f / denom;
    float4 o;
    o.x = acc.x * inv; o.y = acc.y * inv; o.z = acc.z * inv; o.w = acc.w * inv;
    *(float4*)(out + qa) = o;
}

extern "C" void kernel_launch(void* const* d_in, const int* in_sizes, int n_in,
                              void* d_out, int out_size, void* d_ws, size_t ws_size,
                              hipStream_t stream) {
    const float* q = (const float*)d_in[0];
    const float* k = (const float*)d_in[1];
    const float* v = (const float*)d_in[2];
    float* outp = (float*)d_out;
    float* kt = (float*)d_ws;                       // 32*4094*64 f32 = 33.5 MB
    float* vt = kt + (size_t)NBH * NINT * D;        // +33.5 MB

    hipLaunchKernelGGL(tree_chunk, dim3(NBH * 64), dim3(256), 0, stream,
                       k, v, kt, vt);
    hipLaunchKernelGGL(tree_top, dim3(NBH), dim3(256), 0, stream, kt, vt);
    hipLaunchKernelGGL(attn, dim3((B * S * 2 * 64) / 256), dim3(256), 0, stream,
                       q, k, v, kt, vt, outp);
}